// Round 1
// 97.795 us; speedup vs baseline: 1.0113x; 1.0113x over previous
//
#include <hip/hip_runtime.h>

// Chamfer, B=4, N=M=8192 fp32 -> scalar. Round 4:
//  - MS 32 -> 64: 2048 blocks = 8 blocks/CU = 32 waves/CU (was 16). Theory: VALU-bound at
//    79% of measured FMA ceiling (m07 103 TF); 4 waves/SIMD leaves issue bubbles from
//    ds_read latency + loop overhead. __launch_bounds__(256,8) caps VGPR at 64 (was 48).
//  - prep kernel fused away: each block premultiplies its own 128-pt Q chunk in LDS
//    (redundant VALU is negligible); P read raw (recovery mul by -0.5 was exact anyway,
//    so arithmetic is bit-identical to round 3). wmin init via hipMemsetAsync(0xFF)
//    (valid +inf for uint-ordered atomicMin since stored values are clamped >= 0).

#define BATCH 4
#define NPTS 8192
#define MS 64                  // m-chunks per direction
#define RPT 8                  // n-points per thread
#define CHUNK (NPTS / MS)      // 128 q-points per block
#define SETPTS (BATCH * NPTS)  // 32768

__global__ __launch_bounds__(256, 8) void chamfer_min_kernel(
    const float* __restrict__ p1, const float* __restrict__ p2,
    unsigned int* __restrict__ wmin) {
  const int mchunk = blockIdx.x;  // 0..MS-1
  const int nblk = blockIdx.y;    // 0..3
  const int zb = blockIdx.z;      // 0..7
  const int dir = zb >> 2;        // 0: P=p1,Q=p2 ; 1: P=p2,Q=p1
  const int b = zb & 3;
  const float* __restrict__ P = (dir ? p2 : p1) + (size_t)b * NPTS * 3;
  const float* __restrict__ Q = (dir ? p1 : p2) + (size_t)b * NPTS * 3;
  unsigned int* __restrict__ wm = wmin + ((size_t)dir * BATCH + b) * NPTS;

  const int t = threadIdx.x;

  // Stage raw Q floats (CHUNK*3 = 384) into LDS, coalesced.
  __shared__ float rawQ[CHUNK * 3];
  __shared__ float4 sQ[CHUNK];
  {
    const float* qb = Q + (size_t)mchunk * (CHUNK * 3);
    rawQ[t] = qb[t];
    if (t < CHUNK * 3 - 256) rawQ[256 + t] = qb[256 + t];
  }

  // Load this thread's 8 P points raw (dense, 12B stride) while Q staging lands.
  float px[RPT], py[RPT], pz[RPT], pw[RPT], acc[RPT];
#pragma unroll
  for (int r = 0; r < RPT; ++r) {
    const int n = nblk * (RPT * 256) + r * 256 + t;
    const float x = P[3 * n], y = P[3 * n + 1], z = P[3 * n + 2];
    px[r] = x;
    py[r] = y;
    pz[r] = z;
    pw[r] = fmaf(x, x, fmaf(y, y, z * z));  // |p|^2 for the epilogue
    acc[r] = INFINITY;                      // min over q of (|q|^2 - 2 p.q)
  }

  __syncthreads();
  // Premultiply Q into sQ: (-2x, -2y, -2z, |q|^2) — same values prep produced.
  if (t < CHUNK) {
    const float x = rawQ[3 * t], y = rawQ[3 * t + 1], z = rawQ[3 * t + 2];
    sQ[t] = make_float4(-2.f * x, -2.f * y, -2.f * z, fmaf(x, x, fmaf(y, y, z * z)));
  }
  __syncthreads();

  for (int j = 0; j < CHUNK; j += 4) {
    const float4 q0 = sQ[j];      // broadcast ds_read_b128, conflict-free
    const float4 q1 = sQ[j + 1];
    const float4 q2 = sQ[j + 2];
    const float4 q3 = sQ[j + 3];
#pragma unroll
    for (int r = 0; r < RPT; ++r) {
      const float c0 = fmaf(px[r], q0.x, fmaf(py[r], q0.y, fmaf(pz[r], q0.z, q0.w)));
      const float c1 = fmaf(px[r], q1.x, fmaf(py[r], q1.y, fmaf(pz[r], q1.z, q1.w)));
      const float c2 = fmaf(px[r], q2.x, fmaf(py[r], q2.y, fmaf(pz[r], q2.z, q2.w)));
      const float c3 = fmaf(px[r], q3.x, fmaf(py[r], q3.y, fmaf(pz[r], q3.z, q3.w)));
      acc[r] = fminf(fminf(acc[r], c0), c1);  // v_min3_f32
      acc[r] = fminf(fminf(acc[r], c2), c3);  // v_min3_f32
    }
  }

#pragma unroll
  for (int r = 0; r < RPT; ++r) {
    const int n = nblk * (RPT * 256) + r * 256 + t;
    const float v = fmaxf(acc[r] + pw[r], 0.f);  // clamp keeps uint-ordered atomicMin valid
    atomicMin(&wm[n], __float_as_uint(v));
  }
}

__global__ __launch_bounds__(256) void chamfer_reduce_kernel(const unsigned int* __restrict__ wmin,
                                                             float* __restrict__ out) {
  // 65536 elements; 64 blocks x 256 threads x 4 elems
  float s = 0.f;
  const int base = blockIdx.x * 1024 + threadIdx.x;
#pragma unroll
  for (int k = 0; k < 4; ++k) s += __uint_as_float(wmin[base + k * 256]);
#pragma unroll
  for (int off = 32; off > 0; off >>= 1) s += __shfl_down(s, off, 64);
  __shared__ float wsum[4];
  const int lane = threadIdx.x & 63, wid = threadIdx.x >> 6;
  if (lane == 0) wsum[wid] = s;
  __syncthreads();
  if (threadIdx.x == 0) atomicAdd(out, wsum[0] + wsum[1] + wsum[2] + wsum[3]);
}

extern "C" void kernel_launch(void* const* d_in, const int* in_sizes, int n_in,
                              void* d_out, int out_size, void* d_ws, size_t ws_size,
                              hipStream_t stream) {
  const float* p1 = (const float*)d_in[0];
  const float* p2 = (const float*)d_in[1];
  float* out = (float*)d_out;
  unsigned int* wmin = (unsigned int*)d_ws;  // 256 KB

  // 0xFFFFFFFF > any clamped-nonnegative float bit pattern: valid +inf for atomicMin.
  hipMemsetAsync(wmin, 0xFF, 2 * SETPTS * sizeof(unsigned int), stream);
  hipMemsetAsync(out, 0, sizeof(float), stream);

  dim3 grid(MS, NPTS / (RPT * 256), 2 * BATCH);
  chamfer_min_kernel<<<grid, dim3(256), 0, stream>>>(p1, p2, wmin);

  chamfer_reduce_kernel<<<dim3(64), dim3(256), 0, stream>>>(wmin, out);
}